// Round 1
// baseline (764.251 us; speedup 1.0000x reference)
//
#include <hip/hip_runtime.h>
#include <math.h>

#define L_SEQ   2048
#define DM      1024
#define DI      2048
#define NST     16
#define LC      64      // chunk length for scan
#define NCHUNK  32      // L_SEQ / LC
#define XP_LD   36      // padded leading dim for xp (33 cols)

__device__ __forceinline__ float silu_f(float x) {
  return x / (1.0f + __expf(-x));
}
__device__ __forceinline__ float softplus_f(float x) {
  return x > 20.0f ? x : log1pf(__expf(x));
}

// ---------------------------------------------------------------------------
// Generic C = A(MxK, row-major) * B(NxK, row-major)^T, fp32 vector FMA.
// 64x64 tile, BK=16, 256 threads, 4x4 micro-tile per thread.
// grid = (N/64, M/64)
// ---------------------------------------------------------------------------
__global__ __launch_bounds__(256) void gemm_bt_f32(
    const float* __restrict__ A, const float* __restrict__ B,
    float* __restrict__ C, int K, int ldc) {
  __shared__ float As[16][68];   // [k][m], padded
  __shared__ float Bs[16][68];   // [k][n], padded
  const int tid = threadIdx.x;
  const int tx = tid & 15, ty = tid >> 4;
  const int m0 = blockIdx.y * 64, n0 = blockIdx.x * 64;
  const int r  = tid >> 2;           // 0..63 row within tile
  const int c4 = (tid & 3) << 2;     // 0,4,8,12
  const float* Ap = A + (size_t)(m0 + r) * K + c4;
  const float* Bp = B + (size_t)(n0 + r) * K + c4;
  float acc[4][4] = {};
  for (int k0 = 0; k0 < K; k0 += 16) {
    float4 va = *(const float4*)(Ap + k0);
    float4 vb = *(const float4*)(Bp + k0);
    As[c4+0][r] = va.x; As[c4+1][r] = va.y; As[c4+2][r] = va.z; As[c4+3][r] = va.w;
    Bs[c4+0][r] = vb.x; Bs[c4+1][r] = vb.y; Bs[c4+2][r] = vb.z; Bs[c4+3][r] = vb.w;
    __syncthreads();
#pragma unroll
    for (int kk = 0; kk < 16; ++kk) {
      float4 a4 = *(const float4*)&As[kk][ty << 2];
      float4 b4 = *(const float4*)&Bs[kk][tx << 2];
      float a[4] = {a4.x, a4.y, a4.z, a4.w};
      float b[4] = {b4.x, b4.y, b4.z, b4.w};
#pragma unroll
      for (int i = 0; i < 4; ++i)
#pragma unroll
        for (int j = 0; j < 4; ++j)
          acc[i][j] = fmaf(a[i], b[j], acc[i][j]);
    }
    __syncthreads();
  }
#pragma unroll
  for (int i = 0; i < 4; ++i) {
    float4 v = {acc[i][0], acc[i][1], acc[i][2], acc[i][3]};
    *(float4*)&C[(size_t)(m0 + (ty << 2) + i) * ldc + n0 + (tx << 2)] = v;
  }
}

// ---------------------------------------------------------------------------
// Depthwise causal conv (D_CONV=4) + bias + silu.
// xz is (L, 4096): cols [0,2048) = x_ssm.  xc out (L, 2048).
// grid = (DI/256, L)
// ---------------------------------------------------------------------------
__global__ __launch_bounds__(256) void conv_silu_k(
    const float* __restrict__ xz, const float* __restrict__ cw,
    const float* __restrict__ cb, float* __restrict__ xc) {
  const int d = blockIdx.x * 256 + threadIdx.x;
  const int l = blockIdx.y;
  const float w0 = cw[d*4+0], w1 = cw[d*4+1], w2 = cw[d*4+2], w3 = cw[d*4+3];
  float acc = cb[d];
  if (l >= 3) acc = fmaf(w0, xz[(size_t)(l-3)*4096 + d], acc);
  if (l >= 2) acc = fmaf(w1, xz[(size_t)(l-2)*4096 + d], acc);
  if (l >= 1) acc = fmaf(w2, xz[(size_t)(l-1)*4096 + d], acc);
  acc = fmaf(w3, xz[(size_t)l*4096 + d], acc);
  xc[(size_t)l*DI + d] = silu_f(acc);
}

// ---------------------------------------------------------------------------
// xp = xc (L x 2048) @ x_proj_w(33 x 2048)^T -> (L x 33), stored stride 36.
// Block = 256 thr (4 waves) handles 64 rows; wave w owns 9 cols (pad to 36).
// grid = L/64
// ---------------------------------------------------------------------------
__global__ __launch_bounds__(256) void gemm_xp_k(
    const float* __restrict__ xc, const float* __restrict__ Wxp,
    float* __restrict__ xp) {
  const int L0   = blockIdx.x * 64;
  const int wv   = threadIdx.x >> 6;   // wave 0..3
  const int lane = threadIdx.x & 63;   // row within tile
  __shared__ float xcs[64][65];
  __shared__ float Ws[36][64];
  float acc[9] = {};
  for (int k0 = 0; k0 < DI; k0 += 64) {
    {
      int r = threadIdx.x >> 2;
      int cbase = (threadIdx.x & 3) * 16;
#pragma unroll
      for (int q = 0; q < 4; ++q) {
        float4 v = *(const float4*)&xc[(size_t)(L0 + r) * DI + k0 + cbase + q*4];
        xcs[r][cbase + q*4 + 0] = v.x; xcs[r][cbase + q*4 + 1] = v.y;
        xcs[r][cbase + q*4 + 2] = v.z; xcs[r][cbase + q*4 + 3] = v.w;
      }
    }
    for (int idx = threadIdx.x; idx < 36 * 16; idx += 256) {
      int j = idx >> 4; int cc = (idx & 15) << 2;
      float4 v = make_float4(0.f, 0.f, 0.f, 0.f);
      if (j < 33) v = *(const float4*)&Wxp[(size_t)j * DI + k0 + cc];
      *(float4*)&Ws[j][cc] = v;
    }
    __syncthreads();
#pragma unroll 4
    for (int kk = 0; kk < 64; kk += 4) {
      float4 wr[9];
#pragma unroll
      for (int jj = 0; jj < 9; ++jj) wr[jj] = *(const float4*)&Ws[wv*9 + jj][kk];
      float a0 = xcs[lane][kk+0], a1 = xcs[lane][kk+1];
      float a2 = xcs[lane][kk+2], a3 = xcs[lane][kk+3];
#pragma unroll
      for (int jj = 0; jj < 9; ++jj) {
        acc[jj] = fmaf(a0, wr[jj].x, acc[jj]);
        acc[jj] = fmaf(a1, wr[jj].y, acc[jj]);
        acc[jj] = fmaf(a2, wr[jj].z, acc[jj]);
        acc[jj] = fmaf(a3, wr[jj].w, acc[jj]);
      }
    }
    __syncthreads();
  }
  const int l = L0 + lane;
#pragma unroll
  for (int jj = 0; jj < 9; ++jj) {
    int j = wv * 9 + jj;
    if (j < 33) xp[(size_t)l * XP_LD + j] = acc[jj];
  }
}

// ---------------------------------------------------------------------------
// Scan phase A: per-chunk local scan from h=0. Emits P = prod(dA), Q = h_end.
// grid = (DI/256, NCHUNK)
// ---------------------------------------------------------------------------
__global__ __launch_bounds__(256) void scan_partial_k(
    const float* __restrict__ xc, const float* __restrict__ xp,
    const float* __restrict__ dtw, const float* __restrict__ dtb,
    const float* __restrict__ A_log,
    float* __restrict__ P, float* __restrict__ Q) {
  const int d = blockIdx.x * 256 + threadIdx.x;
  const int c = blockIdx.y;
  const int l0 = c * LC;
  __shared__ float xps[LC][33];
  for (int idx = threadIdx.x; idx < LC * 33; idx += 256) {
    int rr = idx / 33, cc = idx - rr * 33;
    xps[rr][cc] = xp[(size_t)(l0 + rr) * XP_LD + cc];
  }
  float Ad[NST];
#pragma unroll
  for (int n4 = 0; n4 < NST; n4 += 4) {
    float4 v = *(const float4*)&A_log[(size_t)d * NST + n4];
    Ad[n4+0] = -__expf(v.x); Ad[n4+1] = -__expf(v.y);
    Ad[n4+2] = -__expf(v.z); Ad[n4+3] = -__expf(v.w);
  }
  const float w = dtw[d], b = dtb[d];
  float h[NST], p[NST];
#pragma unroll
  for (int n = 0; n < NST; ++n) { h[n] = 0.f; p[n] = 1.f; }
  __syncthreads();
  const float* xcp = xc + (size_t)l0 * DI + d;
  for (int t = 0; t < LC; ++t) {
    float xcv = xcp[(size_t)t * DI];
    float dt  = softplus_f(fmaf(xps[t][0], w, b));
    float dtx = dt * xcv;
#pragma unroll
    for (int n = 0; n < NST; ++n) {
      float da = __expf(dt * Ad[n]);
      h[n] = fmaf(da, h[n], dtx * xps[t][1 + n]);
      p[n] *= da;
    }
  }
  size_t base = ((size_t)c * DI + d) * NST;
#pragma unroll
  for (int n4 = 0; n4 < NST; n4 += 4) {
    *(float4*)&P[base + n4] = make_float4(p[n4], p[n4+1], p[n4+2], p[n4+3]);
    *(float4*)&Q[base + n4] = make_float4(h[n4], h[n4+1], h[n4+2], h[n4+3]);
  }
}

// ---------------------------------------------------------------------------
// Scan phase B: sequential prefix over chunks. Emits h_start per chunk.
// grid = DI/256
// ---------------------------------------------------------------------------
__global__ __launch_bounds__(256) void scan_prefix_k(
    const float* __restrict__ P, const float* __restrict__ Q,
    float* __restrict__ Hs) {
  const int d = blockIdx.x * 256 + threadIdx.x;
  float h[NST];
#pragma unroll
  for (int n = 0; n < NST; ++n) h[n] = 0.f;
  for (int c = 0; c < NCHUNK; ++c) {
    size_t base = ((size_t)c * DI + d) * NST;
#pragma unroll
    for (int n4 = 0; n4 < NST; n4 += 4) {
      float4 pv = *(const float4*)&P[base + n4];
      float4 qv = *(const float4*)&Q[base + n4];
      *(float4*)&Hs[base + n4] = make_float4(h[n4], h[n4+1], h[n4+2], h[n4+3]);
      h[n4+0] = fmaf(pv.x, h[n4+0], qv.x);
      h[n4+1] = fmaf(pv.y, h[n4+1], qv.y);
      h[n4+2] = fmaf(pv.z, h[n4+2], qv.z);
      h[n4+3] = fmaf(pv.w, h[n4+3], qv.w);
    }
  }
}

// ---------------------------------------------------------------------------
// Scan phase C: re-run chunk seeded with h_start, produce
// ys = (scan_y + xc*D) * silu(z).   grid = (DI/256, NCHUNK)
// ---------------------------------------------------------------------------
__global__ __launch_bounds__(256) void scan_final_k(
    const float* __restrict__ xc, const float* __restrict__ xp,
    const float* __restrict__ dtw, const float* __restrict__ dtb,
    const float* __restrict__ A_log, const float* __restrict__ Dp,
    const float* __restrict__ Hs, const float* __restrict__ xz,
    float* __restrict__ ys) {
  const int d = blockIdx.x * 256 + threadIdx.x;
  const int c = blockIdx.y;
  const int l0 = c * LC;
  __shared__ float xps[LC][33];
  for (int idx = threadIdx.x; idx < LC * 33; idx += 256) {
    int rr = idx / 33, cc = idx - rr * 33;
    xps[rr][cc] = xp[(size_t)(l0 + rr) * XP_LD + cc];
  }
  float Ad[NST];
#pragma unroll
  for (int n4 = 0; n4 < NST; n4 += 4) {
    float4 v = *(const float4*)&A_log[(size_t)d * NST + n4];
    Ad[n4+0] = -__expf(v.x); Ad[n4+1] = -__expf(v.y);
    Ad[n4+2] = -__expf(v.z); Ad[n4+3] = -__expf(v.w);
  }
  const float w = dtw[d], b = dtb[d], Dd = Dp[d];
  float h[NST];
  size_t hb = ((size_t)c * DI + d) * NST;
#pragma unroll
  for (int n4 = 0; n4 < NST; n4 += 4)
    *(float4*)&h[n4] = *(const float4*)&Hs[hb + n4];
  __syncthreads();
  for (int t = 0; t < LC; ++t) {
    const int l = l0 + t;
    float xcv = xc[(size_t)l * DI + d];
    float dt  = softplus_f(fmaf(xps[t][0], w, b));
    float dtx = dt * xcv;
    float y = 0.f;
#pragma unroll
    for (int n = 0; n < NST; ++n) {
      float da = __expf(dt * Ad[n]);
      h[n] = fmaf(da, h[n], dtx * xps[t][1 + n]);
      y = fmaf(h[n], xps[t][17 + n], y);
    }
    y = fmaf(xcv, Dd, y);
    float zv = xz[(size_t)l * 4096 + 2048 + d];
    ys[(size_t)l * DI + d] = y * silu_f(zv);
  }
}

// ---------------------------------------------------------------------------
extern "C" void kernel_launch(void* const* d_in, const int* in_sizes, int n_in,
                              void* d_out, int out_size, void* d_ws, size_t ws_size,
                              hipStream_t stream) {
  const float* x    = (const float*)d_in[0];   // (2048,1024)
  const float* W1   = (const float*)d_in[1];   // (4096,1024)
  const float* cw   = (const float*)d_in[2];   // (2048,1,4)
  const float* cb   = (const float*)d_in[3];   // (2048,)
  const float* Wxp  = (const float*)d_in[4];   // (33,2048)
  const float* dtw  = (const float*)d_in[5];   // (2048,1)
  const float* dtb  = (const float*)d_in[6];   // (2048,)
  const float* Alog = (const float*)d_in[7];   // (2048,16)
  const float* Dp   = (const float*)d_in[8];   // (2048,)
  const float* Wout = (const float*)d_in[9];   // (1024,2048)
  float* out = (float*)d_out;                  // (2048,1024)

  float* xz = (float*)d_ws;              // 2048*4096
  float* xc = xz + (size_t)L_SEQ * 4096; // 2048*2048
  float* xp = xc + (size_t)L_SEQ * DI;   // 2048*36
  float* P  = xp + (size_t)L_SEQ * XP_LD;
  float* Q  = P  + (size_t)NCHUNK * DI * NST;
  float* Hs = Q  + (size_t)NCHUNK * DI * NST;
  float* ys = Hs + (size_t)NCHUNK * DI * NST;

  // 1. xz = x @ in_proj_w^T
  gemm_bt_f32<<<dim3(4096/64, L_SEQ/64), 256, 0, stream>>>(x, W1, xz, DM, 4096);
  // 2. depthwise conv + silu
  conv_silu_k<<<dim3(DI/256, L_SEQ), 256, 0, stream>>>(xz, cw, cb, xc);
  // 3. xp = xc @ x_proj_w^T
  gemm_xp_k<<<L_SEQ/64, 256, 0, stream>>>(xc, Wxp, xp);
  // 4. chunked selective scan
  scan_partial_k<<<dim3(DI/256, NCHUNK), 256, 0, stream>>>(xc, xp, dtw, dtb, Alog, P, Q);
  scan_prefix_k<<<DI/256, 256, 0, stream>>>(P, Q, Hs);
  scan_final_k<<<dim3(DI/256, NCHUNK), 256, 0, stream>>>(xc, xp, dtw, dtb, Alog, Dp, Hs, xz, ys);
  // 5. out = ys @ out_proj_w^T
  gemm_bt_f32<<<dim3(1024/64, L_SEQ/64), 256, 0, stream>>>(ys, Wout, out, DI, 1024);
}

// Round 3
// 470.930 us; speedup vs baseline: 1.6229x; 1.6229x over previous
//
#include <hip/hip_runtime.h>
#include <math.h>

#define L_SEQ   2048
#define DM      1024
#define DI      2048
#define NST     16
#define LC      64      // chunk length for scan
#define NCHUNK  32      // L_SEQ / LC
#define XP_LD   36      // padded leading dim for xp (33 cols)

typedef short s16x8 __attribute__((ext_vector_type(8)));
typedef float f32x4 __attribute__((ext_vector_type(4)));

__device__ __forceinline__ float silu_f(float x) {
  return x / (1.0f + __expf(-x));
}
__device__ __forceinline__ float softplus_f(float x) {
  return x > 20.0f ? x : log1pf(__expf(x));
}
// fp32 -> bf16 RNE
__device__ __forceinline__ ushort f2bf(float f) {
  unsigned int u = __float_as_uint(f);
  unsigned int r = (u + 0x7fffu + ((u >> 16) & 1u)) >> 16;
  return (ushort)r;
}
__device__ __forceinline__ void gload_lds16(const void* g, void* lds) {
  __builtin_amdgcn_global_load_lds(
      (const __attribute__((address_space(1))) unsigned int*)g,
      (__attribute__((address_space(3))) unsigned int*)lds,
      16, 0, 0);
}

// ---------------------------------------------------------------------------
// fp32 -> bf16 conversion, 4 elems/thread
// ---------------------------------------------------------------------------
__global__ __launch_bounds__(256) void cvt_bf16_k(
    const float* __restrict__ in, ushort* __restrict__ out, int n4) {
  int i = blockIdx.x * 256 + threadIdx.x;
  if (i >= n4) return;
  float4 v = ((const float4*)in)[i];
  ushort4 o;
  o.x = f2bf(v.x); o.y = f2bf(v.y); o.z = f2bf(v.z); o.w = f2bf(v.w);
  ((ushort4*)out)[i] = o;
}

// ---------------------------------------------------------------------------
// bf16 MFMA GEMM: C(MxN fp32) = A(MxK bf16,row-major) * B(NxK bf16,row-major)^T
// m97 structure: BK=32, 256 thr = 4 waves (2x2), wave tile = MFRAG*16 x 64.
// BM = MFRAG*32, BN = 128.  grid = (N/128, M/BM).
// ---------------------------------------------------------------------------
template <int MFRAG>
__global__ __launch_bounds__(256) void gemm_mfma_bf16(
    const ushort* __restrict__ A, const ushort* __restrict__ B,
    float* __restrict__ C, int K, int ldc) {
  constexpr int BM = MFRAG * 32;
  __shared__ ushort As[BM * 32];
  __shared__ ushort Bs[128 * 32];
  const int tid  = threadIdx.x;
  const int lane = tid & 63;
  const int wv   = tid >> 6;
  const int wr   = wv >> 1;   // wave row 0..1
  const int wc   = wv & 1;    // wave col 0..1
  const int m0 = blockIdx.y * BM;
  const int n0 = blockIdx.x * 128;

  f32x4 acc[MFRAG][4] = {};

  const int kc = (tid & 3) * 8;   // bf16-element offset of this thread's 16B chunk

  for (int k0 = 0; k0 < K; k0 += 32) {
    __syncthreads();
    // stage A tile: BM rows x 32 cols bf16 = BM*4 chunks of 16B
#pragma unroll
    for (int q = 0; q < BM / 64; ++q) {
      int id = q * 256 + tid;
      int m  = id >> 2;
      gload_lds16(A + (size_t)(m0 + m) * K + k0 + kc, (char*)As + id * 16);
    }
    // stage B tile: 128 rows x 32 cols
#pragma unroll
    for (int q = 0; q < 2; ++q) {
      int id = q * 256 + tid;
      int n  = id >> 2;
      gload_lds16(B + (size_t)(n0 + n) * K + k0 + kc, (char*)Bs + id * 16);
    }
    __syncthreads();   // drains vmcnt before reads

    s16x8 af[MFRAG], bfr[4];
#pragma unroll
    for (int m = 0; m < MFRAG; ++m)
      af[m] = *(const s16x8*)&As[(wr * MFRAG * 16 + m * 16 + (lane & 15)) * 32 + (lane >> 4) * 8];
#pragma unroll
    for (int n = 0; n < 4; ++n)
      bfr[n] = *(const s16x8*)&Bs[(wc * 64 + n * 16 + (lane & 15)) * 32 + (lane >> 4) * 8];
#pragma unroll
    for (int m = 0; m < MFRAG; ++m)
#pragma unroll
      for (int n = 0; n < 4; ++n)
        acc[m][n] = __builtin_amdgcn_mfma_f32_16x16x32_bf16(af[m], bfr[n], acc[m][n], 0, 0, 0);
  }
  // epilogue: C/D layout col=lane&15, row=(lane>>4)*4+reg  [m89-verified]
  const int cr = (lane >> 4) * 4;
  const int cc = lane & 15;
#pragma unroll
  for (int m = 0; m < MFRAG; ++m) {
    int gr0 = m0 + wr * MFRAG * 16 + m * 16 + cr;
#pragma unroll
    for (int n = 0; n < 4; ++n) {
      int gc = n0 + wc * 64 + n * 16 + cc;
#pragma unroll
      for (int r = 0; r < 4; ++r)
        C[(size_t)(gr0 + r) * ldc + gc] = acc[m][n][r];
    }
  }
}

// ---------------------------------------------------------------------------
// Depthwise causal conv (D_CONV=4) + bias + silu.
// ---------------------------------------------------------------------------
__global__ __launch_bounds__(256) void conv_silu_k(
    const float* __restrict__ xz, const float* __restrict__ cw,
    const float* __restrict__ cb, float* __restrict__ xc) {
  const int d = blockIdx.x * 256 + threadIdx.x;
  const int l = blockIdx.y;
  const float w0 = cw[d*4+0], w1 = cw[d*4+1], w2 = cw[d*4+2], w3 = cw[d*4+3];
  float acc = cb[d];
  if (l >= 3) acc = fmaf(w0, xz[(size_t)(l-3)*4096 + d], acc);
  if (l >= 2) acc = fmaf(w1, xz[(size_t)(l-2)*4096 + d], acc);
  if (l >= 1) acc = fmaf(w2, xz[(size_t)(l-1)*4096 + d], acc);
  acc = fmaf(w3, xz[(size_t)l*4096 + d], acc);
  xc[(size_t)l*DI + d] = silu_f(acc);
}

// ---------------------------------------------------------------------------
// xp = xc (L x 2048) @ x_proj_w(33 x 2048)^T -> (L x 33), stored stride 36.
// ---------------------------------------------------------------------------
__global__ __launch_bounds__(256) void gemm_xp_k(
    const float* __restrict__ xc, const float* __restrict__ Wxp,
    float* __restrict__ xp) {
  const int L0   = blockIdx.x * 64;
  const int wv   = threadIdx.x >> 6;
  const int lane = threadIdx.x & 63;
  __shared__ float xcs[64][65];
  __shared__ float Ws[36][64];
  float acc[9] = {};
  for (int k0 = 0; k0 < DI; k0 += 64) {
    {
      int r = threadIdx.x >> 2;
      int cbase = (threadIdx.x & 3) * 16;
#pragma unroll
      for (int q = 0; q < 4; ++q) {
        float4 v = *(const float4*)&xc[(size_t)(L0 + r) * DI + k0 + cbase + q*4];
        xcs[r][cbase + q*4 + 0] = v.x; xcs[r][cbase + q*4 + 1] = v.y;
        xcs[r][cbase + q*4 + 2] = v.z; xcs[r][cbase + q*4 + 3] = v.w;
      }
    }
    for (int idx = threadIdx.x; idx < 36 * 16; idx += 256) {
      int j = idx >> 4; int cc = (idx & 15) << 2;
      float4 v = make_float4(0.f, 0.f, 0.f, 0.f);
      if (j < 33) v = *(const float4*)&Wxp[(size_t)j * DI + k0 + cc];
      *(float4*)&Ws[j][cc] = v;
    }
    __syncthreads();
#pragma unroll 4
    for (int kk = 0; kk < 64; kk += 4) {
      float4 wr[9];
#pragma unroll
      for (int jj = 0; jj < 9; ++jj) wr[jj] = *(const float4*)&Ws[wv*9 + jj][kk];
      float a0 = xcs[lane][kk+0], a1 = xcs[lane][kk+1];
      float a2 = xcs[lane][kk+2], a3 = xcs[lane][kk+3];
#pragma unroll
      for (int jj = 0; jj < 9; ++jj) {
        acc[jj] = fmaf(a0, wr[jj].x, acc[jj]);
        acc[jj] = fmaf(a1, wr[jj].y, acc[jj]);
        acc[jj] = fmaf(a2, wr[jj].z, acc[jj]);
        acc[jj] = fmaf(a3, wr[jj].w, acc[jj]);
      }
    }
    __syncthreads();
  }
  const int l = L0 + lane;
#pragma unroll
  for (int jj = 0; jj < 9; ++jj) {
    int j = wv * 9 + jj;
    if (j < 33) xp[(size_t)l * XP_LD + j] = acc[jj];
  }
}

// ---------------------------------------------------------------------------
// Scan phase A: per-chunk local scan from h=0. Emits P = prod(dA), Q = h_end.
// ---------------------------------------------------------------------------
__global__ __launch_bounds__(256) void scan_partial_k(
    const float* __restrict__ xc, const float* __restrict__ xp,
    const float* __restrict__ dtw, const float* __restrict__ dtb,
    const float* __restrict__ A_log,
    float* __restrict__ P, float* __restrict__ Q) {
  const int d = blockIdx.x * 256 + threadIdx.x;
  const int c = blockIdx.y;
  const int l0 = c * LC;
  __shared__ float xps[LC][33];
  for (int idx = threadIdx.x; idx < LC * 33; idx += 256) {
    int rr = idx / 33, cc = idx - rr * 33;
    xps[rr][cc] = xp[(size_t)(l0 + rr) * XP_LD + cc];
  }
  float Ad[NST];
#pragma unroll
  for (int n4 = 0; n4 < NST; n4 += 4) {
    float4 v = *(const float4*)&A_log[(size_t)d * NST + n4];
    Ad[n4+0] = -__expf(v.x); Ad[n4+1] = -__expf(v.y);
    Ad[n4+2] = -__expf(v.z); Ad[n4+3] = -__expf(v.w);
  }
  const float w = dtw[d], b = dtb[d];
  float h[NST], p[NST];
#pragma unroll
  for (int n = 0; n < NST; ++n) { h[n] = 0.f; p[n] = 1.f; }
  __syncthreads();
  const float* xcp = xc + (size_t)l0 * DI + d;
  for (int t = 0; t < LC; ++t) {
    float xcv = xcp[(size_t)t * DI];
    float dt  = softplus_f(fmaf(xps[t][0], w, b));
    float dtx = dt * xcv;
#pragma unroll
    for (int n = 0; n < NST; ++n) {
      float da = __expf(dt * Ad[n]);
      h[n] = fmaf(da, h[n], dtx * xps[t][1 + n]);
      p[n] *= da;
    }
  }
  size_t base = ((size_t)c * DI + d) * NST;
#pragma unroll
  for (int n4 = 0; n4 < NST; n4 += 4) {
    *(float4*)&P[base + n4] = make_float4(p[n4], p[n4+1], p[n4+2], p[n4+3]);
    *(float4*)&Q[base + n4] = make_float4(h[n4], h[n4+1], h[n4+2], h[n4+3]);
  }
}

// ---------------------------------------------------------------------------
// Scan phase B: sequential prefix over chunks. Emits h_start per chunk.
// ---------------------------------------------------------------------------
__global__ __launch_bounds__(256) void scan_prefix_k(
    const float* __restrict__ P, const float* __restrict__ Q,
    float* __restrict__ Hs) {
  const int d = blockIdx.x * 256 + threadIdx.x;
  float h[NST];
#pragma unroll
  for (int n = 0; n < NST; ++n) h[n] = 0.f;
  for (int c = 0; c < NCHUNK; ++c) {
    size_t base = ((size_t)c * DI + d) * NST;
#pragma unroll
    for (int n4 = 0; n4 < NST; n4 += 4) {
      float4 pv = *(const float4*)&P[base + n4];
      float4 qv = *(const float4*)&Q[base + n4];
      *(float4*)&Hs[base + n4] = make_float4(h[n4], h[n4+1], h[n4+2], h[n4+3]);
      h[n4+0] = fmaf(pv.x, h[n4+0], qv.x);
      h[n4+1] = fmaf(pv.y, h[n4+1], qv.y);
      h[n4+2] = fmaf(pv.z, h[n4+2], qv.z);
      h[n4+3] = fmaf(pv.w, h[n4+3], qv.w);
    }
  }
}

// ---------------------------------------------------------------------------
// Scan phase C: seeded re-scan; ys (bf16) = (scan_y + xc*D) * silu(z).
// ---------------------------------------------------------------------------
__global__ __launch_bounds__(256) void scan_final_k(
    const float* __restrict__ xc, const float* __restrict__ xp,
    const float* __restrict__ dtw, const float* __restrict__ dtb,
    const float* __restrict__ A_log, const float* __restrict__ Dp,
    const float* __restrict__ Hs, const float* __restrict__ xz,
    ushort* __restrict__ ys) {
  const int d = blockIdx.x * 256 + threadIdx.x;
  const int c = blockIdx.y;
  const int l0 = c * LC;
  __shared__ float xps[LC][33];
  for (int idx = threadIdx.x; idx < LC * 33; idx += 256) {
    int rr = idx / 33, cc = idx - rr * 33;
    xps[rr][cc] = xp[(size_t)(l0 + rr) * XP_LD + cc];
  }
  float Ad[NST];
#pragma unroll
  for (int n4 = 0; n4 < NST; n4 += 4) {
    float4 v = *(const float4*)&A_log[(size_t)d * NST + n4];
    Ad[n4+0] = -__expf(v.x); Ad[n4+1] = -__expf(v.y);
    Ad[n4+2] = -__expf(v.z); Ad[n4+3] = -__expf(v.w);
  }
  const float w = dtw[d], b = dtb[d], Dd = Dp[d];
  float h[NST];
  size_t hb = ((size_t)c * DI + d) * NST;
#pragma unroll
  for (int n4 = 0; n4 < NST; n4 += 4)
    *(float4*)&h[n4] = *(const float4*)&Hs[hb + n4];
  __syncthreads();
  for (int t = 0; t < LC; ++t) {
    const int l = l0 + t;
    float xcv = xc[(size_t)l * DI + d];
    float dt  = softplus_f(fmaf(xps[t][0], w, b));
    float dtx = dt * xcv;
    float y = 0.f;
#pragma unroll
    for (int n = 0; n < NST; ++n) {
      float da = __expf(dt * Ad[n]);
      h[n] = fmaf(da, h[n], dtx * xps[t][1 + n]);
      y = fmaf(h[n], xps[t][17 + n], y);
    }
    y = fmaf(xcv, Dd, y);
    float zv = xz[(size_t)l * 4096 + 2048 + d];
    ys[(size_t)l * DI + d] = f2bf(y * silu_f(zv));
  }
}

// ---------------------------------------------------------------------------
extern "C" void kernel_launch(void* const* d_in, const int* in_sizes, int n_in,
                              void* d_out, int out_size, void* d_ws, size_t ws_size,
                              hipStream_t stream) {
  const float* x    = (const float*)d_in[0];   // (2048,1024)
  const float* W1   = (const float*)d_in[1];   // (4096,1024)
  const float* cw   = (const float*)d_in[2];   // (2048,1,4)
  const float* cb   = (const float*)d_in[3];   // (2048,)
  const float* Wxp  = (const float*)d_in[4];   // (33,2048)
  const float* dtw  = (const float*)d_in[5];   // (2048,1)
  const float* dtb  = (const float*)d_in[6];   // (2048,)
  const float* Alog = (const float*)d_in[7];   // (2048,16)
  const float* Dp   = (const float*)d_in[8];   // (2048,)
  const float* Wout = (const float*)d_in[9];   // (1024,2048)
  float* out = (float*)d_out;                  // (2048,1024)

  char* w = (char*)d_ws;
  float* xz = (float*)w;                                  // 33,554,432 B
  float* xc = (float*)(w + 33554432);                     // 16,777,216 B
  float* xp = (float*)(w + 50331648);                     //    294,912 B
  // union region (P/Q/Hs alias x_bf/W1_bf — conversions dead before scan)
  float*  P       = (float*)(w + 50626560);               //  4 MiB
  float*  Q       = P + (size_t)NCHUNK * DI * NST;        //  4 MiB
  float*  Hs      = Q + (size_t)NCHUNK * DI * NST;        //  4 MiB
  ushort* x_bf    = (ushort*)(w + 50626560);              //  4 MiB (alias P)
  ushort* W1_bf   = (ushort*)(w + 50626560 + 4194304);    //  8 MiB (alias Q,Hs)
  ushort* Wout_bf = (ushort*)(w + 50626560 + 12582912);   //  4 MiB
  ushort* ys_bf   = (ushort*)(w + 50626560 + 16777216);   //  8 MiB
  // total = 75,792,384 B

  // 0. fp32 -> bf16 conversions
  cvt_bf16_k<<<2048, 256, 0, stream>>>(x,    x_bf,    2048*1024/4);
  cvt_bf16_k<<<4096, 256, 0, stream>>>(W1,   W1_bf,   4096*1024/4);
  cvt_bf16_k<<<2048, 256, 0, stream>>>(Wout, Wout_bf, 1024*2048/4);
  // 1. xz = x @ in_proj_w^T   (MFMA bf16)
  gemm_mfma_bf16<4><<<dim3(4096/128, 2048/128), 256, 0, stream>>>(x_bf, W1_bf, xz, DM, 4096);
  // 2. depthwise conv + silu
  conv_silu_k<<<dim3(DI/256, L_SEQ), 256, 0, stream>>>(xz, cw, cb, xc);
  // 3. xp = xc @ x_proj_w^T
  gemm_xp_k<<<L_SEQ/64, 256, 0, stream>>>(xc, Wxp, xp);
  // 4. chunked selective scan
  scan_partial_k<<<dim3(DI/256, NCHUNK), 256, 0, stream>>>(xc, xp, dtw, dtb, Alog, P, Q);
  scan_prefix_k<<<DI/256, 256, 0, stream>>>(P, Q, Hs);
  scan_final_k<<<dim3(DI/256, NCHUNK), 256, 0, stream>>>(xc, xp, dtw, dtb, Alog, Dp, Hs, xz, ys_bf);
  // 5. out = ys @ out_proj_w^T   (MFMA bf16, BM=64 for 256-block grid)
  gemm_mfma_bf16<2><<<dim3(1024/128, 2048/64), 256, 0, stream>>>(ys_bf, Wout_bf, out, DI, 1024);
}

// Round 4
// 348.551 us; speedup vs baseline: 2.1927x; 1.3511x over previous
//
#include <hip/hip_runtime.h>
#include <math.h>

#define L_SEQ   2048
#define DM      1024
#define DI      2048
#define NST     16
#define LC      64      // chunk length for scan
#define NCHUNK  32      // L_SEQ / LC
#define XP_LD   36      // padded leading dim for xp (33 cols)
#define KSPLIT  8       // K-splits for gemm_xp

typedef short s16x8 __attribute__((ext_vector_type(8)));
typedef float f32x4 __attribute__((ext_vector_type(4)));

__device__ __forceinline__ float silu_f(float x) {
  return x / (1.0f + __expf(-x));
}
__device__ __forceinline__ float softplus_f(float x) {
  return x > 20.0f ? x : log1pf(__expf(x));
}
// fp32 -> bf16 RNE
__device__ __forceinline__ ushort f2bf(float f) {
  unsigned int u = __float_as_uint(f);
  unsigned int r = (u + 0x7fffu + ((u >> 16) & 1u)) >> 16;
  return (ushort)r;
}
__device__ __forceinline__ void gload_lds16(const void* g, void* lds) {
  __builtin_amdgcn_global_load_lds(
      (const __attribute__((address_space(1))) unsigned int*)g,
      (__attribute__((address_space(3))) unsigned int*)lds,
      16, 0, 0);
}

// ---------------------------------------------------------------------------
// fp32 -> bf16 conversion, 4 elems/thread
// ---------------------------------------------------------------------------
__global__ __launch_bounds__(256) void cvt_bf16_k(
    const float* __restrict__ in, ushort* __restrict__ out, int n4) {
  int i = blockIdx.x * 256 + threadIdx.x;
  if (i >= n4) return;
  float4 v = ((const float4*)in)[i];
  ushort4 o;
  o.x = f2bf(v.x); o.y = f2bf(v.y); o.z = f2bf(v.z); o.w = f2bf(v.w);
  ((ushort4*)out)[i] = o;
}

// ---------------------------------------------------------------------------
// bf16 MFMA GEMM: C(MxN fp32) = A(MxK bf16,row-major) * B(NxK bf16,row-major)^T
// m97 structure: BK=32, 256 thr = 4 waves (2x2), wave tile = MFRAG*16 x 64.
// BM = MFRAG*32, BN = 128.  grid = (N/128, M/BM).
// ---------------------------------------------------------------------------
template <int MFRAG>
__global__ __launch_bounds__(256) void gemm_mfma_bf16(
    const ushort* __restrict__ A, const ushort* __restrict__ B,
    float* __restrict__ C, int K, int ldc) {
  constexpr int BM = MFRAG * 32;
  __shared__ ushort As[BM * 32];
  __shared__ ushort Bs[128 * 32];
  const int tid  = threadIdx.x;
  const int lane = tid & 63;
  const int wv   = tid >> 6;
  const int wr   = wv >> 1;   // wave row 0..1
  const int wc   = wv & 1;    // wave col 0..1
  const int m0 = blockIdx.y * BM;
  const int n0 = blockIdx.x * 128;

  f32x4 acc[MFRAG][4] = {};

  const int kc = (tid & 3) * 8;   // bf16-element offset of this thread's 16B chunk

  for (int k0 = 0; k0 < K; k0 += 32) {
    __syncthreads();
    // stage A tile: BM rows x 32 cols bf16 = BM*4 chunks of 16B
#pragma unroll
    for (int q = 0; q < BM / 64; ++q) {
      int id = q * 256 + tid;
      int m  = id >> 2;
      gload_lds16(A + (size_t)(m0 + m) * K + k0 + kc, (char*)As + id * 16);
    }
    // stage B tile: 128 rows x 32 cols
#pragma unroll
    for (int q = 0; q < 2; ++q) {
      int id = q * 256 + tid;
      int n  = id >> 2;
      gload_lds16(B + (size_t)(n0 + n) * K + k0 + kc, (char*)Bs + id * 16);
    }
    __syncthreads();   // drains vmcnt before reads

    s16x8 af[MFRAG], bfr[4];
#pragma unroll
    for (int m = 0; m < MFRAG; ++m)
      af[m] = *(const s16x8*)&As[(wr * MFRAG * 16 + m * 16 + (lane & 15)) * 32 + (lane >> 4) * 8];
#pragma unroll
    for (int n = 0; n < 4; ++n)
      bfr[n] = *(const s16x8*)&Bs[(wc * 64 + n * 16 + (lane & 15)) * 32 + (lane >> 4) * 8];
#pragma unroll
    for (int m = 0; m < MFRAG; ++m)
#pragma unroll
      for (int n = 0; n < 4; ++n)
        acc[m][n] = __builtin_amdgcn_mfma_f32_16x16x32_bf16(af[m], bfr[n], acc[m][n], 0, 0, 0);
  }
  // epilogue: C/D layout col=lane&15, row=(lane>>4)*4+reg  [m89-verified]
  const int cr = (lane >> 4) * 4;
  const int cc = lane & 15;
#pragma unroll
  for (int m = 0; m < MFRAG; ++m) {
    int gr0 = m0 + wr * MFRAG * 16 + m * 16 + cr;
#pragma unroll
    for (int n = 0; n < 4; ++n) {
      int gc = n0 + wc * 64 + n * 16 + cc;
#pragma unroll
      for (int r = 0; r < 4; ++r)
        C[(size_t)(gr0 + r) * ldc + gc] = acc[m][n][r];
    }
  }
}

// ---------------------------------------------------------------------------
// Depthwise causal conv (D_CONV=4) + bias + silu.
// ---------------------------------------------------------------------------
__global__ __launch_bounds__(256) void conv_silu_k(
    const float* __restrict__ xz, const float* __restrict__ cw,
    const float* __restrict__ cb, float* __restrict__ xc) {
  const int d = blockIdx.x * 256 + threadIdx.x;
  const int l = blockIdx.y;
  const float w0 = cw[d*4+0], w1 = cw[d*4+1], w2 = cw[d*4+2], w3 = cw[d*4+3];
  float acc = cb[d];
  if (l >= 3) acc = fmaf(w0, xz[(size_t)(l-3)*4096 + d], acc);
  if (l >= 2) acc = fmaf(w1, xz[(size_t)(l-2)*4096 + d], acc);
  if (l >= 1) acc = fmaf(w2, xz[(size_t)(l-1)*4096 + d], acc);
  acc = fmaf(w3, xz[(size_t)l*4096 + d], acc);
  xc[(size_t)l*DI + d] = silu_f(acc);
}

// ---------------------------------------------------------------------------
// xp partials: split-K over KSPLIT slices of 256.
// grid = (L/64, KSPLIT).  Per block: 64 rows x 33 cols, K-slice 256.
// ---------------------------------------------------------------------------
__global__ __launch_bounds__(256) void gemm_xp_k(
    const float* __restrict__ xc, const float* __restrict__ Wxp,
    float* __restrict__ xp_part) {
  const int L0   = blockIdx.x * 64;
  const int ks   = blockIdx.y;
  const int wv   = threadIdx.x >> 6;
  const int lane = threadIdx.x & 63;
  __shared__ float xcs[64][65];
  __shared__ float Ws[36][64];
  float acc[9] = {};
  const int kbeg = ks * (DI / KSPLIT);
  const int kend = kbeg + DI / KSPLIT;
  for (int k0 = kbeg; k0 < kend; k0 += 64) {
    {
      int r = threadIdx.x >> 2;
      int cbase = (threadIdx.x & 3) * 16;
#pragma unroll
      for (int q = 0; q < 4; ++q) {
        float4 v = *(const float4*)&xc[(size_t)(L0 + r) * DI + k0 + cbase + q*4];
        xcs[r][cbase + q*4 + 0] = v.x; xcs[r][cbase + q*4 + 1] = v.y;
        xcs[r][cbase + q*4 + 2] = v.z; xcs[r][cbase + q*4 + 3] = v.w;
      }
    }
    for (int idx = threadIdx.x; idx < 36 * 16; idx += 256) {
      int j = idx >> 4; int cc = (idx & 15) << 2;
      float4 v = make_float4(0.f, 0.f, 0.f, 0.f);
      if (j < 33) v = *(const float4*)&Wxp[(size_t)j * DI + k0 + cc];
      *(float4*)&Ws[j][cc] = v;
    }
    __syncthreads();
#pragma unroll 4
    for (int kk = 0; kk < 64; kk += 4) {
      float4 wr[9];
#pragma unroll
      for (int jj = 0; jj < 9; ++jj) wr[jj] = *(const float4*)&Ws[wv*9 + jj][kk];
      float a0 = xcs[lane][kk+0], a1 = xcs[lane][kk+1];
      float a2 = xcs[lane][kk+2], a3 = xcs[lane][kk+3];
#pragma unroll
      for (int jj = 0; jj < 9; ++jj) {
        acc[jj] = fmaf(a0, wr[jj].x, acc[jj]);
        acc[jj] = fmaf(a1, wr[jj].y, acc[jj]);
        acc[jj] = fmaf(a2, wr[jj].z, acc[jj]);
        acc[jj] = fmaf(a3, wr[jj].w, acc[jj]);
      }
    }
    __syncthreads();
  }
  const int l = L0 + lane;
#pragma unroll
  for (int jj = 0; jj < 9; ++jj) {
    int j = wv * 9 + jj;
    if (j < 33)
      xp_part[(size_t)ks * L_SEQ * XP_LD + (size_t)l * XP_LD + j] = acc[jj];
  }
}

// ---------------------------------------------------------------------------
// Reduce split-K partials: xp = sum_ks xp_part[ks].
// grid = L_SEQ*XP_LD/256 = 288
// ---------------------------------------------------------------------------
__global__ __launch_bounds__(256) void reduce_xp_k(
    const float* __restrict__ part, float* __restrict__ xp) {
  int i = blockIdx.x * 256 + threadIdx.x;
  float s = 0.f;
#pragma unroll
  for (int ks = 0; ks < KSPLIT; ++ks)
    s += part[(size_t)ks * L_SEQ * XP_LD + i];
  xp[i] = s;
}

// ---------------------------------------------------------------------------
// Scan phase A: per-chunk local scan from h=0. Emits P = prod(dA), Q = h_end.
// ---------------------------------------------------------------------------
__global__ __launch_bounds__(256) void scan_partial_k(
    const float* __restrict__ xc, const float* __restrict__ xp,
    const float* __restrict__ dtw, const float* __restrict__ dtb,
    const float* __restrict__ A_log,
    float* __restrict__ P, float* __restrict__ Q) {
  const int d = blockIdx.x * 256 + threadIdx.x;
  const int c = blockIdx.y;
  const int l0 = c * LC;
  __shared__ float xps[LC][33];
  for (int idx = threadIdx.x; idx < LC * 33; idx += 256) {
    int rr = idx / 33, cc = idx - rr * 33;
    xps[rr][cc] = xp[(size_t)(l0 + rr) * XP_LD + cc];
  }
  float Ad[NST];
#pragma unroll
  for (int n4 = 0; n4 < NST; n4 += 4) {
    float4 v = *(const float4*)&A_log[(size_t)d * NST + n4];
    Ad[n4+0] = -__expf(v.x); Ad[n4+1] = -__expf(v.y);
    Ad[n4+2] = -__expf(v.z); Ad[n4+3] = -__expf(v.w);
  }
  const float w = dtw[d], b = dtb[d];
  float h[NST], p[NST];
#pragma unroll
  for (int n = 0; n < NST; ++n) { h[n] = 0.f; p[n] = 1.f; }
  __syncthreads();
  const float* xcp = xc + (size_t)l0 * DI + d;
  for (int t = 0; t < LC; ++t) {
    float xcv = xcp[(size_t)t * DI];
    float dt  = softplus_f(fmaf(xps[t][0], w, b));
    float dtx = dt * xcv;
#pragma unroll
    for (int n = 0; n < NST; ++n) {
      float da = __expf(dt * Ad[n]);
      h[n] = fmaf(da, h[n], dtx * xps[t][1 + n]);
      p[n] *= da;
    }
  }
  size_t base = ((size_t)c * DI + d) * NST;
#pragma unroll
  for (int n4 = 0; n4 < NST; n4 += 4) {
    *(float4*)&P[base + n4] = make_float4(p[n4], p[n4+1], p[n4+2], p[n4+3]);
    *(float4*)&Q[base + n4] = make_float4(h[n4], h[n4+1], h[n4+2], h[n4+3]);
  }
}

// ---------------------------------------------------------------------------
// Scan phase B: sequential prefix over chunks. Emits h_start per chunk.
// ---------------------------------------------------------------------------
__global__ __launch_bounds__(256) void scan_prefix_k(
    const float* __restrict__ P, const float* __restrict__ Q,
    float* __restrict__ Hs) {
  const int d = blockIdx.x * 256 + threadIdx.x;
  float h[NST];
#pragma unroll
  for (int n = 0; n < NST; ++n) h[n] = 0.f;
  for (int c = 0; c < NCHUNK; ++c) {
    size_t base = ((size_t)c * DI + d) * NST;
#pragma unroll
    for (int n4 = 0; n4 < NST; n4 += 4) {
      float4 pv = *(const float4*)&P[base + n4];
      float4 qv = *(const float4*)&Q[base + n4];
      *(float4*)&Hs[base + n4] = make_float4(h[n4], h[n4+1], h[n4+2], h[n4+3]);
      h[n4+0] = fmaf(pv.x, h[n4+0], qv.x);
      h[n4+1] = fmaf(pv.y, h[n4+1], qv.y);
      h[n4+2] = fmaf(pv.z, h[n4+2], qv.z);
      h[n4+3] = fmaf(pv.w, h[n4+3], qv.w);
    }
  }
}

// ---------------------------------------------------------------------------
// Scan phase C: seeded re-scan; ys (bf16) = (scan_y + xc*D) * silu(z).
// ---------------------------------------------------------------------------
__global__ __launch_bounds__(256) void scan_final_k(
    const float* __restrict__ xc, const float* __restrict__ xp,
    const float* __restrict__ dtw, const float* __restrict__ dtb,
    const float* __restrict__ A_log, const float* __restrict__ Dp,
    const float* __restrict__ Hs, const float* __restrict__ xz,
    ushort* __restrict__ ys) {
  const int d = blockIdx.x * 256 + threadIdx.x;
  const int c = blockIdx.y;
  const int l0 = c * LC;
  __shared__ float xps[LC][33];
  for (int idx = threadIdx.x; idx < LC * 33; idx += 256) {
    int rr = idx / 33, cc = idx - rr * 33;
    xps[rr][cc] = xp[(size_t)(l0 + rr) * XP_LD + cc];
  }
  float Ad[NST];
#pragma unroll
  for (int n4 = 0; n4 < NST; n4 += 4) {
    float4 v = *(const float4*)&A_log[(size_t)d * NST + n4];
    Ad[n4+0] = -__expf(v.x); Ad[n4+1] = -__expf(v.y);
    Ad[n4+2] = -__expf(v.z); Ad[n4+3] = -__expf(v.w);
  }
  const float w = dtw[d], b = dtb[d], Dd = Dp[d];
  float h[NST];
  size_t hb = ((size_t)c * DI + d) * NST;
#pragma unroll
  for (int n4 = 0; n4 < NST; n4 += 4)
    *(float4*)&h[n4] = *(const float4*)&Hs[hb + n4];
  __syncthreads();
  for (int t = 0; t < LC; ++t) {
    const int l = l0 + t;
    float xcv = xc[(size_t)l * DI + d];
    float dt  = softplus_f(fmaf(xps[t][0], w, b));
    float dtx = dt * xcv;
    float y = 0.f;
#pragma unroll
    for (int n = 0; n < NST; ++n) {
      float da = __expf(dt * Ad[n]);
      h[n] = fmaf(da, h[n], dtx * xps[t][1 + n]);
      y = fmaf(h[n], xps[t][17 + n], y);
    }
    y = fmaf(xcv, Dd, y);
    float zv = xz[(size_t)l * 4096 + 2048 + d];
    ys[(size_t)l * DI + d] = f2bf(y * silu_f(zv));
  }
}

// ---------------------------------------------------------------------------
extern "C" void kernel_launch(void* const* d_in, const int* in_sizes, int n_in,
                              void* d_out, int out_size, void* d_ws, size_t ws_size,
                              hipStream_t stream) {
  const float* x    = (const float*)d_in[0];   // (2048,1024)
  const float* W1   = (const float*)d_in[1];   // (4096,1024)
  const float* cw   = (const float*)d_in[2];   // (2048,1,4)
  const float* cb   = (const float*)d_in[3];   // (2048,)
  const float* Wxp  = (const float*)d_in[4];   // (33,2048)
  const float* dtw  = (const float*)d_in[5];   // (2048,1)
  const float* dtb  = (const float*)d_in[6];   // (2048,)
  const float* Alog = (const float*)d_in[7];   // (2048,16)
  const float* Dp   = (const float*)d_in[8];   // (2048,)
  const float* Wout = (const float*)d_in[9];   // (1024,2048)
  float* out = (float*)d_out;                  // (2048,1024)

  char* w = (char*)d_ws;
  float* xz = (float*)w;                                  // 33,554,432 B
  float* xc = (float*)(w + 33554432);                     // 16,777,216 B
  float* xp = (float*)(w + 50331648);                     //    294,912 B
  // union region (P/Q/Hs alias x_bf/W1_bf — conversions dead before scan)
  float*  P       = (float*)(w + 50626560);               //  4 MiB
  float*  Q       = P + (size_t)NCHUNK * DI * NST;        //  4 MiB
  float*  Hs      = Q + (size_t)NCHUNK * DI * NST;        //  4 MiB
  ushort* x_bf    = (ushort*)(w + 50626560);              //  4 MiB (alias P)
  ushort* W1_bf   = (ushort*)(w + 50626560 + 4194304);    //  8 MiB (alias Q,Hs)
  ushort* Wout_bf = (ushort*)(w + 50626560 + 12582912);   //  4 MiB
  ushort* ys_bf   = (ushort*)(w + 50626560 + 16777216);   //  8 MiB
  float*  xp_part = (float*)(w + 75792384);               //  2,359,296 B
  // total = 78,151,680 B

  // 0. fp32 -> bf16 conversions
  cvt_bf16_k<<<2048, 256, 0, stream>>>(x,    x_bf,    2048*1024/4);
  cvt_bf16_k<<<4096, 256, 0, stream>>>(W1,   W1_bf,   4096*1024/4);
  cvt_bf16_k<<<2048, 256, 0, stream>>>(Wout, Wout_bf, 1024*2048/4);
  // 1. xz = x @ in_proj_w^T   (MFMA bf16)
  gemm_mfma_bf16<4><<<dim3(4096/128, 2048/128), 256, 0, stream>>>(x_bf, W1_bf, xz, DM, 4096);
  // 2. depthwise conv + silu
  conv_silu_k<<<dim3(DI/256, L_SEQ), 256, 0, stream>>>(xz, cw, cb, xc);
  // 3. xp = xc @ x_proj_w^T  (split-K partials + reduce)
  gemm_xp_k<<<dim3(L_SEQ/64, KSPLIT), 256, 0, stream>>>(xc, Wxp, xp_part);
  reduce_xp_k<<<L_SEQ*XP_LD/256, 256, 0, stream>>>(xp_part, xp);
  // 4. chunked selective scan
  scan_partial_k<<<dim3(DI/256, NCHUNK), 256, 0, stream>>>(xc, xp, dtw, dtb, Alog, P, Q);
  scan_prefix_k<<<DI/256, 256, 0, stream>>>(P, Q, Hs);
  scan_final_k<<<dim3(DI/256, NCHUNK), 256, 0, stream>>>(xc, xp, dtw, dtb, Alog, Dp, Hs, xz, ys_bf);
  // 5. out = ys @ out_proj_w^T   (MFMA bf16, BM=64 for 256-block grid)
  gemm_mfma_bf16<2><<<dim3(1024/128, 2048/64), 256, 0, stream>>>(ys_bf, Wout_bf, out, DI, 1024);
}

// Round 5
// 304.230 us; speedup vs baseline: 2.5121x; 1.1457x over previous
//
#include <hip/hip_runtime.h>
#include <math.h>

#define L_SEQ   2048
#define DM      1024
#define DI      2048
#define NST     16
#define LC      32      // chunk length for scan
#define NCHUNK  64      // L_SEQ / LC
#define XP_LD   36      // padded leading dim for xp (33 cols)
#define KSPLIT  8       // K-splits for gemm_xp

typedef short s16x8 __attribute__((ext_vector_type(8)));
typedef float f32x4 __attribute__((ext_vector_type(4)));

__device__ __forceinline__ float silu_f(float x) {
  return x / (1.0f + __expf(-x));
}
__device__ __forceinline__ float softplus_f(float x) {
  return x > 20.0f ? x : log1pf(__expf(x));
}
// fp32 -> bf16 RNE
__device__ __forceinline__ ushort f2bf(float f) {
  unsigned int u = __float_as_uint(f);
  unsigned int r = (u + 0x7fffu + ((u >> 16) & 1u)) >> 16;
  return (ushort)r;
}
__device__ __forceinline__ void gload_lds16(const void* g, void* lds) {
  __builtin_amdgcn_global_load_lds(
      (const __attribute__((address_space(1))) unsigned int*)g,
      (__attribute__((address_space(3))) unsigned int*)lds,
      16, 0, 0);
}

// ---------------------------------------------------------------------------
// fp32 -> bf16 conversion, 4 elems/thread
// ---------------------------------------------------------------------------
__global__ __launch_bounds__(256) void cvt_bf16_k(
    const float* __restrict__ in, ushort* __restrict__ out, int n4) {
  int i = blockIdx.x * 256 + threadIdx.x;
  if (i >= n4) return;
  float4 v = ((const float4*)in)[i];
  ushort4 o;
  o.x = f2bf(v.x); o.y = f2bf(v.y); o.z = f2bf(v.z); o.w = f2bf(v.w);
  ((ushort4*)out)[i] = o;
}

// ---------------------------------------------------------------------------
// bf16 MFMA GEMM: C(MxN fp32) = A(MxK bf16,row-major) * B(NxK bf16,row-major)^T
// m97 structure: BK=32, 256 thr = 4 waves (2x2), wave tile = MFRAG*16 x 64.
// BM = MFRAG*32, BN = 128.  grid = (N/128, M/BM).
// ---------------------------------------------------------------------------
template <int MFRAG>
__global__ __launch_bounds__(256) void gemm_mfma_bf16(
    const ushort* __restrict__ A, const ushort* __restrict__ B,
    float* __restrict__ C, int K, int ldc) {
  constexpr int BM = MFRAG * 32;
  __shared__ ushort As[BM * 32];
  __shared__ ushort Bs[128 * 32];
  const int tid  = threadIdx.x;
  const int lane = tid & 63;
  const int wv   = tid >> 6;
  const int wr   = wv >> 1;   // wave row 0..1
  const int wc   = wv & 1;    // wave col 0..1
  const int m0 = blockIdx.y * BM;
  const int n0 = blockIdx.x * 128;

  f32x4 acc[MFRAG][4] = {};

  const int kc = (tid & 3) * 8;   // bf16-element offset of this thread's 16B chunk

  for (int k0 = 0; k0 < K; k0 += 32) {
    __syncthreads();
    // stage A tile: BM rows x 32 cols bf16 = BM*4 chunks of 16B
#pragma unroll
    for (int q = 0; q < BM / 64; ++q) {
      int id = q * 256 + tid;
      int m  = id >> 2;
      gload_lds16(A + (size_t)(m0 + m) * K + k0 + kc, (char*)As + id * 16);
    }
    // stage B tile: 128 rows x 32 cols
#pragma unroll
    for (int q = 0; q < 2; ++q) {
      int id = q * 256 + tid;
      int n  = id >> 2;
      gload_lds16(B + (size_t)(n0 + n) * K + k0 + kc, (char*)Bs + id * 16);
    }
    __syncthreads();   // drains vmcnt before reads

    s16x8 af[MFRAG], bfr[4];
#pragma unroll
    for (int m = 0; m < MFRAG; ++m)
      af[m] = *(const s16x8*)&As[(wr * MFRAG * 16 + m * 16 + (lane & 15)) * 32 + (lane >> 4) * 8];
#pragma unroll
    for (int n = 0; n < 4; ++n)
      bfr[n] = *(const s16x8*)&Bs[(wc * 64 + n * 16 + (lane & 15)) * 32 + (lane >> 4) * 8];
#pragma unroll
    for (int m = 0; m < MFRAG; ++m)
#pragma unroll
      for (int n = 0; n < 4; ++n)
        acc[m][n] = __builtin_amdgcn_mfma_f32_16x16x32_bf16(af[m], bfr[n], acc[m][n], 0, 0, 0);
  }
  // epilogue: C/D layout col=lane&15, row=(lane>>4)*4+reg  [m89-verified]
  const int cr = (lane >> 4) * 4;
  const int cc = lane & 15;
#pragma unroll
  for (int m = 0; m < MFRAG; ++m) {
    int gr0 = m0 + wr * MFRAG * 16 + m * 16 + cr;
#pragma unroll
    for (int n = 0; n < 4; ++n) {
      int gc = n0 + wc * 64 + n * 16 + cc;
#pragma unroll
      for (int r = 0; r < 4; ++r)
        C[(size_t)(gr0 + r) * ldc + gc] = acc[m][n][r];
    }
  }
}

// ---------------------------------------------------------------------------
// Depthwise causal conv (D_CONV=4) + bias + silu.
// ---------------------------------------------------------------------------
__global__ __launch_bounds__(256) void conv_silu_k(
    const float* __restrict__ xz, const float* __restrict__ cw,
    const float* __restrict__ cb, float* __restrict__ xc) {
  const int d = blockIdx.x * 256 + threadIdx.x;
  const int l = blockIdx.y;
  const float w0 = cw[d*4+0], w1 = cw[d*4+1], w2 = cw[d*4+2], w3 = cw[d*4+3];
  float acc = cb[d];
  if (l >= 3) acc = fmaf(w0, xz[(size_t)(l-3)*4096 + d], acc);
  if (l >= 2) acc = fmaf(w1, xz[(size_t)(l-2)*4096 + d], acc);
  if (l >= 1) acc = fmaf(w2, xz[(size_t)(l-1)*4096 + d], acc);
  acc = fmaf(w3, xz[(size_t)l*4096 + d], acc);
  xc[(size_t)l*DI + d] = silu_f(acc);
}

// ---------------------------------------------------------------------------
// xp partials: split-K over KSPLIT slices of 256.
// grid = (L/64, KSPLIT).  Per block: 64 rows x 33 cols, K-slice 256.
// ---------------------------------------------------------------------------
__global__ __launch_bounds__(256) void gemm_xp_k(
    const float* __restrict__ xc, const float* __restrict__ Wxp,
    float* __restrict__ xp_part) {
  const int L0   = blockIdx.x * 64;
  const int ks   = blockIdx.y;
  const int wv   = threadIdx.x >> 6;
  const int lane = threadIdx.x & 63;
  __shared__ float xcs[64][65];
  __shared__ float Ws[36][64];
  float acc[9] = {};
  const int kbeg = ks * (DI / KSPLIT);
  const int kend = kbeg + DI / KSPLIT;
  for (int k0 = kbeg; k0 < kend; k0 += 64) {
    {
      int r = threadIdx.x >> 2;
      int cbase = (threadIdx.x & 3) * 16;
#pragma unroll
      for (int q = 0; q < 4; ++q) {
        float4 v = *(const float4*)&xc[(size_t)(L0 + r) * DI + k0 + cbase + q*4];
        xcs[r][cbase + q*4 + 0] = v.x; xcs[r][cbase + q*4 + 1] = v.y;
        xcs[r][cbase + q*4 + 2] = v.z; xcs[r][cbase + q*4 + 3] = v.w;
      }
    }
    for (int idx = threadIdx.x; idx < 36 * 16; idx += 256) {
      int j = idx >> 4; int cc = (idx & 15) << 2;
      float4 v = make_float4(0.f, 0.f, 0.f, 0.f);
      if (j < 33) v = *(const float4*)&Wxp[(size_t)j * DI + k0 + cc];
      *(float4*)&Ws[j][cc] = v;
    }
    __syncthreads();
#pragma unroll 4
    for (int kk = 0; kk < 64; kk += 4) {
      float4 wr[9];
#pragma unroll
      for (int jj = 0; jj < 9; ++jj) wr[jj] = *(const float4*)&Ws[wv*9 + jj][kk];
      float a0 = xcs[lane][kk+0], a1 = xcs[lane][kk+1];
      float a2 = xcs[lane][kk+2], a3 = xcs[lane][kk+3];
#pragma unroll
      for (int jj = 0; jj < 9; ++jj) {
        acc[jj] = fmaf(a0, wr[jj].x, acc[jj]);
        acc[jj] = fmaf(a1, wr[jj].y, acc[jj]);
        acc[jj] = fmaf(a2, wr[jj].z, acc[jj]);
        acc[jj] = fmaf(a3, wr[jj].w, acc[jj]);
      }
    }
    __syncthreads();
  }
  const int l = L0 + lane;
#pragma unroll
  for (int jj = 0; jj < 9; ++jj) {
    int j = wv * 9 + jj;
    if (j < 33)
      xp_part[(size_t)ks * L_SEQ * XP_LD + (size_t)l * XP_LD + j] = acc[jj];
  }
}

// ---------------------------------------------------------------------------
// Reduce split-K partials: xp = sum_ks xp_part[ks].
// ---------------------------------------------------------------------------
__global__ __launch_bounds__(256) void reduce_xp_k(
    const float* __restrict__ part, float* __restrict__ xp) {
  int i = blockIdx.x * 256 + threadIdx.x;
  float s = 0.f;
#pragma unroll
  for (int ks = 0; ks < KSPLIT; ++ks)
    s += part[(size_t)ks * L_SEQ * XP_LD + i];
  xp[i] = s;
}

// ---------------------------------------------------------------------------
// Scan phase A: per-chunk local scan from h=0, n-split x2 (8 states/thread).
// Emits P = prod(dA), Q = h_end.  grid = (DI/128, NCHUNK), 256 thr.
// ---------------------------------------------------------------------------
__global__ __launch_bounds__(256) void scan_partial_k(
    const float* __restrict__ xc, const float* __restrict__ xp,
    const float* __restrict__ dtw, const float* __restrict__ dtb,
    const float* __restrict__ A_log,
    float* __restrict__ P, float* __restrict__ Q) {
  const int tid = threadIdx.x;
  const int d   = blockIdx.x * 128 + (tid >> 1);
  const int nb  = (tid & 1) * 8;
  const int c   = blockIdx.y;
  const int l0  = c * LC;
  __shared__ float xps[LC][33];
  for (int idx = tid; idx < LC * 33; idx += 256) {
    int rr = idx / 33, cc = idx - rr * 33;
    xps[rr][cc] = xp[(size_t)(l0 + rr) * XP_LD + cc];
  }
  float Ad[8];
#pragma unroll
  for (int j4 = 0; j4 < 8; j4 += 4) {
    float4 v = *(const float4*)&A_log[(size_t)d * NST + nb + j4];
    Ad[j4+0] = -__expf(v.x); Ad[j4+1] = -__expf(v.y);
    Ad[j4+2] = -__expf(v.z); Ad[j4+3] = -__expf(v.w);
  }
  const float w = dtw[d], b = dtb[d];
  float h[8], p[8];
#pragma unroll
  for (int n = 0; n < 8; ++n) { h[n] = 0.f; p[n] = 1.f; }
  __syncthreads();
  const float* xcp = xc + (size_t)l0 * DI + d;
  for (int t = 0; t < LC; ++t) {
    float xcv = xcp[(size_t)t * DI];
    float dt  = softplus_f(fmaf(xps[t][0], w, b));
    float dtx = dt * xcv;
#pragma unroll
    for (int n = 0; n < 8; ++n) {
      float da = __expf(dt * Ad[n]);
      h[n] = fmaf(da, h[n], dtx * xps[t][1 + nb + n]);
      p[n] *= da;
    }
  }
  size_t base = ((size_t)c * DI + d) * NST + nb;
  *(float4*)&P[base]     = make_float4(p[0], p[1], p[2], p[3]);
  *(float4*)&P[base + 4] = make_float4(p[4], p[5], p[6], p[7]);
  *(float4*)&Q[base]     = make_float4(h[0], h[1], h[2], h[3]);
  *(float4*)&Q[base + 4] = make_float4(h[4], h[5], h[6], h[7]);
}

// ---------------------------------------------------------------------------
// Scan phase B: sequential prefix over chunks, thread per (d, n4).
// QHs is transformed IN PLACE: Q[c] (h_end local) -> Hs[c] (h_start global).
// grid = DI*NST/4/256 = 32 blocks.
// ---------------------------------------------------------------------------
__global__ __launch_bounds__(256) void scan_prefix_k(
    const float* __restrict__ P, float* __restrict__ QHs) {
  const int g = blockIdx.x * 256 + threadIdx.x;   // 0..8191
  const int d = g >> 2;
  const int q = (g & 3) << 2;
  float4 h = make_float4(0.f, 0.f, 0.f, 0.f);
#pragma unroll 8
  for (int c = 0; c < NCHUNK; ++c) {
    size_t base = ((size_t)c * DI + d) * NST + q;
    float4 pv = *(const float4*)&P[base];
    float4 qv = *(const float4*)&QHs[base];
    *(float4*)&QHs[base] = h;   // h_start for chunk c (read-before-write, same thread)
    h.x = fmaf(pv.x, h.x, qv.x);
    h.y = fmaf(pv.y, h.y, qv.y);
    h.z = fmaf(pv.z, h.z, qv.z);
    h.w = fmaf(pv.w, h.w, qv.w);
  }
}

// ---------------------------------------------------------------------------
// Scan phase C: seeded re-scan, n-split x2; y reduced via shfl_xor(1).
// ys (bf16) = (scan_y + xc*D) * silu(z).  grid = (DI/128, NCHUNK).
// ---------------------------------------------------------------------------
__global__ __launch_bounds__(256) void scan_final_k(
    const float* __restrict__ xc, const float* __restrict__ xp,
    const float* __restrict__ dtw, const float* __restrict__ dtb,
    const float* __restrict__ A_log, const float* __restrict__ Dp,
    const float* __restrict__ Hs, const float* __restrict__ xz,
    ushort* __restrict__ ys) {
  const int tid  = threadIdx.x;
  const int d    = blockIdx.x * 128 + (tid >> 1);
  const int half = tid & 1;
  const int nb   = half * 8;
  const int c    = blockIdx.y;
  const int l0   = c * LC;
  __shared__ float xps[LC][33];
  for (int idx = tid; idx < LC * 33; idx += 256) {
    int rr = idx / 33, cc = idx - rr * 33;
    xps[rr][cc] = xp[(size_t)(l0 + rr) * XP_LD + cc];
  }
  float Ad[8];
#pragma unroll
  for (int j4 = 0; j4 < 8; j4 += 4) {
    float4 v = *(const float4*)&A_log[(size_t)d * NST + nb + j4];
    Ad[j4+0] = -__expf(v.x); Ad[j4+1] = -__expf(v.y);
    Ad[j4+2] = -__expf(v.z); Ad[j4+3] = -__expf(v.w);
  }
  const float w = dtw[d], b = dtb[d], Dd = Dp[d];
  float h[8];
  size_t hb = ((size_t)c * DI + d) * NST + nb;
  *(float4*)&h[0] = *(const float4*)&Hs[hb];
  *(float4*)&h[4] = *(const float4*)&Hs[hb + 4];
  __syncthreads();
  for (int t = 0; t < LC; ++t) {
    const int l = l0 + t;
    float xcv = xc[(size_t)l * DI + d];
    float dt  = softplus_f(fmaf(xps[t][0], w, b));
    float dtx = dt * xcv;
    float y = 0.f;
#pragma unroll
    for (int n = 0; n < 8; ++n) {
      float da = __expf(dt * Ad[n]);
      h[n] = fmaf(da, h[n], dtx * xps[t][1 + nb + n]);
      y = fmaf(h[n], xps[t][17 + nb + n], y);
    }
    y += __shfl_xor(y, 1);
    if (half == 0) {
      y = fmaf(xcv, Dd, y);
      float zv = xz[(size_t)l * 4096 + 2048 + d];
      ys[(size_t)l * DI + d] = f2bf(y * silu_f(zv));
    }
  }
}

// ---------------------------------------------------------------------------
extern "C" void kernel_launch(void* const* d_in, const int* in_sizes, int n_in,
                              void* d_out, int out_size, void* d_ws, size_t ws_size,
                              hipStream_t stream) {
  const float* x    = (const float*)d_in[0];   // (2048,1024)
  const float* W1   = (const float*)d_in[1];   // (4096,1024)
  const float* cw   = (const float*)d_in[2];   // (2048,1,4)
  const float* cb   = (const float*)d_in[3];   // (2048,)
  const float* Wxp  = (const float*)d_in[4];   // (33,2048)
  const float* dtw  = (const float*)d_in[5];   // (2048,1)
  const float* dtb  = (const float*)d_in[6];   // (2048,)
  const float* Alog = (const float*)d_in[7];   // (2048,16)
  const float* Dp   = (const float*)d_in[8];   // (2048,)
  const float* Wout = (const float*)d_in[9];   // (1024,2048)
  float* out = (float*)d_out;                  // (2048,1024)

  char* w = (char*)d_ws;
  float*  xz      = (float*)w;                    // [0, 33554432)
  float*  xc      = (float*)(w + 33554432);       // [33554432, 50331648)
  float*  xp      = (float*)(w + 50331648);       // [50331648, 50626560)
  // --- aliased region (lifetimes ordered by stream) ---
  ushort* x_bf    = (ushort*)(w + 50626560);      //  4 MiB   } dead after GEMM1
  ushort* W1_bf   = (ushort*)(w + 54820864);      //  8 MiB   }
  float*  xp_part = (float*)(w + 50626560);       //  2.25 MiB, dead after reduce_xp
  float*  P       = (float*)(w + 50626560);       //  8 MiB, written by scan_partial
  float*  QHs     = (float*)(w + 59015168);       //  8 MiB, Q then Hs in place
  // --- persistent tail ---
  ushort* Wout_bf = (ushort*)(w + 67403776);      //  4 MiB
  ushort* ys_bf   = (ushort*)(w + 71598080);      //  8 MiB
  // total = 79,986,688 B (== R0's proven footprint)

  // 0. fp32 -> bf16 conversions
  cvt_bf16_k<<<2048, 256, 0, stream>>>(x,    x_bf,    2048*1024/4);
  cvt_bf16_k<<<4096, 256, 0, stream>>>(W1,   W1_bf,   4096*1024/4);
  cvt_bf16_k<<<2048, 256, 0, stream>>>(Wout, Wout_bf, 1024*2048/4);
  // 1. xz = x @ in_proj_w^T   (MFMA bf16)
  gemm_mfma_bf16<4><<<dim3(4096/128, 2048/128), 256, 0, stream>>>(x_bf, W1_bf, xz, DM, 4096);
  // 2. depthwise conv + silu
  conv_silu_k<<<dim3(DI/256, L_SEQ), 256, 0, stream>>>(xz, cw, cb, xc);
  // 3. xp = xc @ x_proj_w^T  (split-K partials + reduce)
  gemm_xp_k<<<dim3(L_SEQ/64, KSPLIT), 256, 0, stream>>>(xc, Wxp, xp_part);
  reduce_xp_k<<<L_SEQ*XP_LD/256, 256, 0, stream>>>(xp_part, xp);
  // 4. chunked selective scan (n-split x2, Hs in place of Q)
  scan_partial_k<<<dim3(DI/128, NCHUNK), 256, 0, stream>>>(xc, xp, dtw, dtb, Alog, P, QHs);
  scan_prefix_k<<<DI*NST/4/256, 256, 0, stream>>>(P, QHs);
  scan_final_k<<<dim3(DI/128, NCHUNK), 256, 0, stream>>>(xc, xp, dtw, dtb, Alog, Dp, QHs, xz, ys_bf);
  // 5. out = ys @ out_proj_w^T   (MFMA bf16, BM=64 for 256-block grid)
  gemm_mfma_bf16<2><<<dim3(1024/128, 2048/64), 256, 0, stream>>>(ys_bf, Wout_bf, out, DI, 1024);
}